// Round 1
// 863.801 us; speedup vs baseline: 1.0434x; 1.0434x over previous
//
#include <hip/hip_runtime.h>
#include <stdint.h>

#define B_ 64
#define S_ 2048
#define E_ 1024   // ENC_DIM (= K of main GEMM)
#define D_ 1024   // DEC_DIM
#define A_ 512    // ATT_DIM (= N of main GEMM)
#define M_ (B_*S_)

typedef __attribute__((ext_vector_type(8))) short short8;
typedef __attribute__((ext_vector_type(4))) float floatx4;

typedef __attribute__((address_space(3))) void       lds_void_t;
typedef const __attribute__((address_space(1))) void gbl_void_t;

__device__ __forceinline__ unsigned short f2bf(float f) {
    union { float f; uint32_t u; } v; v.f = f;
    uint32_t u = v.u;
    return (unsigned short)((u + 0x7FFF + ((u >> 16) & 1)) >> 16);  // RNE
}

// ---------------- W_enc fp32 -> bf16, shuffled to staging layout ----------------
// wencS logical layout: [kt(32)][kq(4)][n(512)][e(8)] bf16, i.e. 16B slot
// (kt*2048 + kq*512 + n) holds wenc[n][kt*32 + kq*8 .. +7].
__global__ void k_convert_wenc(const float* __restrict__ wenc,
                               unsigned short* __restrict__ wencS) {
    int slot = blockIdx.x * 256 + threadIdx.x;   // 65536 slots
    int kt = slot >> 11;
    int kq = (slot >> 9) & 3;
    int n  = slot & 511;
    const float4* src = (const float4*)(wenc + (size_t)n * E_ + kt * 32 + kq * 8);
    float4 a = src[0], b = src[1];
    short8 o;
    o[0] = (short)f2bf(a.x); o[1] = (short)f2bf(a.y);
    o[2] = (short)f2bf(a.z); o[3] = (short)f2bf(a.w);
    o[4] = (short)f2bf(b.x); o[5] = (short)f2bf(b.y);
    o[6] = (short)f2bf(b.z); o[7] = (short)f2bf(b.w);
    *(short8*)(wencS + (size_t)slot * 8) = o;
}

// ---------------- dec_feat = decoder_hidden @ W_dec^T  [B, A] ----------------
__global__ void k_dec_feat(const float* __restrict__ dh,
                           const float* __restrict__ wdec,
                           float* __restrict__ df) {
    __shared__ float h[1056];                    // 4 kq-chunks, 264-float stride (pad 8)
    int b  = blockIdx.x >> 3;
    int a0 = (blockIdx.x & 7) * 64;
    int t  = threadIdx.x;
    {
        float4 v = ((const float4*)(dh + (size_t)b * D_))[t];
        int e0 = t * 4;
        *(float4*)(h + (e0 >> 8) * 264 + (e0 & 255)) = v;
    }
    __syncthreads();
    int a  = a0 + (t >> 2);
    int kq = t & 3;
    const float4* wr = (const float4*)(wdec + (size_t)a * D_ + kq * 256);
    const float4* hh = (const float4*)(h + kq * 264);
    float acc = 0.f;
    #pragma unroll 8
    for (int k4 = 0; k4 < 64; ++k4) {
        float4 w = wr[k4];
        float4 x = hh[k4];
        acc += w.x*x.x + w.y*x.y + w.z*x.z + w.w*x.w;
    }
    acc += __shfl_xor(acc, 1);
    acc += __shfl_xor(acc, 2);
    if ((t & 3) == 0) df[b * A_ + a] = acc;
}

// ---------------- per-batch mask compaction (order-preserving) ----------------
// idx[b][0..cnt-1] = s where mask[b][s]==0 (unmasked); idx padded with 0 to S_.
// Degenerate cnt==0: idx = identity (softmax emits uniform weights).
__global__ void k_compact(const int* __restrict__ mask,
                          int* __restrict__ idx,
                          int* __restrict__ cnt) {
    __shared__ int wsum[4];
    __shared__ int s_total;
    int b = blockIdx.x, t = threadIdx.x;
    int lane = t & 63, wv = t >> 6;
    const int* mrow = mask + b * S_;
    int base = t * 8;
    unsigned keep = 0;
    int c = 0;
    #pragma unroll
    for (int i = 0; i < 8; ++i) {
        if (!mrow[base + i]) { keep |= 1u << i; ++c; }
    }
    // wave-inclusive scan
    int v = c;
    #pragma unroll
    for (int o = 1; o < 64; o <<= 1) {
        int u = __shfl_up(v, o);
        if (lane >= o) v += u;
    }
    if (lane == 63) wsum[wv] = v;
    __syncthreads();
    int wbase = 0;
    for (int w = 0; w < wv; ++w) wbase += wsum[w];
    int o = wbase + v - c;                     // exclusive prefix over block
    int* orow = idx + b * S_;
    #pragma unroll
    for (int i = 0; i < 8; ++i)
        if (keep & (1u << i)) orow[o++] = base + i;
    if (t == 255) { int tot = wbase + v; s_total = tot; cnt[b] = tot; }
    __syncthreads();
    int total = s_total;
    if (total == 0) {
        for (int j = t; j < S_; j += 256) orow[j] = j;   // identity fallback
    } else {
        for (int j = total + t; j < S_; j += 256) orow[j] = 0;  // safe pad
    }
}

// ---------------- fused scores GEMM over COMPACTED rows ----------------
// scores_c[b][j] = sum_n W_energy[n]*tanh((enc[idx[b][j]] @ W_enc^T)[n] + df[b,n])
#define BM 64
#define BK 32
#define AROW 40   // padded A row: 32 + 8 elems = 80 B -> conflict-free frag reads

__global__ __launch_bounds__(256, 2) void k_scores(
    const float* __restrict__ enc,            // [M, E] fp32
    const unsigned short* __restrict__ wencS, // shuffled bf16
    const float* __restrict__ df,             // [B, A]
    const float* __restrict__ wE,             // [A]
    const int* __restrict__ idx,              // [B, S] compacted row ids
    const int* __restrict__ cnt,              // [B]
    float* __restrict__ scores)               // [B, S] compact
{
    const int bid = blockIdx.x;
    const int b   = bid >> 5;                 // 32 chunks of 64 rows per batch
    const int c   = bid & 31;
    if (c * BM >= cnt[b]) return;             // uniform early-exit (dead rows)

    __shared__ unsigned short As[BM * AROW];  // 5 KB, [m][k padded]
    __shared__ unsigned short Bs[4 * 512 * 8];// 32 KB, [kq][n][e]
    __shared__ float ps[4][BM];

    const int tid  = threadIdx.x;
    const int wave = tid >> 6;
    const int lane = tid & 63;

    floatx4 acc[4][8];
    #pragma unroll
    for (int i = 0; i < 4; ++i)
        #pragma unroll
        for (int j = 0; j < 8; ++j) acc[i][j] = (floatx4)0.f;

    const int m_a = tid >> 2;                 // 0..63
    const int j_a = tid & 3;                  // k-quad 0..3
    const int row = idx[b * S_ + c * BM + m_a];
    const float* aptr = enc + ((size_t)b * S_ + row) * E_ + j_a * 8;

    const int n0w   = wave * 128;
    const int row16 = lane >> 4;              // 0..3  (= kq of fragment)
    const int col   = lane & 15;

    for (int kt = 0; kt < E_ / BK; ++kt) {
        if (kt) __syncthreads();
        float4 a0 = *(const float4*)(aptr + kt * BK);
        float4 a1 = *(const float4*)(aptr + kt * BK + 4);
        #pragma unroll
        for (int r = 0; r < 8; ++r) {
            int s = r * 256 + tid;
            const unsigned short* g = wencS + ((size_t)kt * 2048 + s) * 8;
            unsigned short* l = &Bs[(size_t)(r * 256 + wave * 64) * 8];
            __builtin_amdgcn_global_load_lds((gbl_void_t*)g, (lds_void_t*)l, 16, 0, 0);
        }
        short8 apk;
        apk[0] = (short)f2bf(a0.x); apk[1] = (short)f2bf(a0.y);
        apk[2] = (short)f2bf(a0.z); apk[3] = (short)f2bf(a0.w);
        apk[4] = (short)f2bf(a1.x); apk[5] = (short)f2bf(a1.y);
        apk[6] = (short)f2bf(a1.z); apk[7] = (short)f2bf(a1.w);
        *(short8*)(&As[m_a * AROW + j_a * 8]) = apk;
        __syncthreads();
        short8 af[4];
        #pragma unroll
        for (int mt = 0; mt < 4; ++mt)
            af[mt] = *(const short8*)(&As[(mt * 16 + col) * AROW + row16 * 8]);
        short8 bfr[8];
        #pragma unroll
        for (int nt = 0; nt < 8; ++nt)
            bfr[nt] = *(const short8*)(&Bs[(size_t)(row16 * 512 + n0w + nt * 16 + col) * 8]);
        #pragma unroll
        for (int mt = 0; mt < 4; ++mt)
            #pragma unroll
            for (int nt = 0; nt < 8; ++nt)
                acc[mt][nt] = __builtin_amdgcn_mfma_f32_16x16x32_bf16(
                    af[mt], bfr[nt], acc[mt][nt], 0, 0, 0);
    }

    // ---- epilogue: tanh(acc + df) * wE, reduce over n ----
    float part[4][4];
    #pragma unroll
    for (int mt = 0; mt < 4; ++mt)
        #pragma unroll
        for (int r = 0; r < 4; ++r) part[mt][r] = 0.f;

    #pragma unroll
    for (int nt = 0; nt < 8; ++nt) {
        int n   = n0w + nt * 16 + col;
        float d = df[b * A_ + n];
        float w = wE[n];
        #pragma unroll
        for (int mt = 0; mt < 4; ++mt)
            #pragma unroll
            for (int r = 0; r < 4; ++r) {
                float x  = acc[mt][nt][r] + d;
                float ex = __expf(2.f * x);
                float th = 1.f - 2.f / (ex + 1.f);   // tanh(x)
                part[mt][r] += w * th;
            }
    }
    #pragma unroll
    for (int mt = 0; mt < 4; ++mt)
        #pragma unroll
        for (int r = 0; r < 4; ++r) {
            float v = part[mt][r];
            v += __shfl_xor(v, 1);
            v += __shfl_xor(v, 2);
            v += __shfl_xor(v, 4);
            v += __shfl_xor(v, 8);
            part[mt][r] = v;
        }
    if (col == 0) {
        #pragma unroll
        for (int mt = 0; mt < 4; ++mt)
            #pragma unroll
            for (int r = 0; r < 4; ++r)
                ps[wave][mt * 16 + row16 * 4 + r] = part[mt][r];
    }
    __syncthreads();
    if (tid < BM)
        scores[b * S_ + c * BM + tid] = ps[0][tid] + ps[1][tid] + ps[2][tid] + ps[3][tid];
}

// ---------------- softmax over compacted scores; scatter to [B,S] ----------------
// weights pre-zeroed (masked slots stay exactly 0, matching exp(min-max)==0).
// wc = compact weights zero-padded to multiple of 128 for k_context.
__global__ void k_softmax(const float* __restrict__ scores,  // compact [B,S]
                          const int* __restrict__ idx,
                          const int* __restrict__ cnt,
                          float* __restrict__ weights,       // [B,S]
                          float* __restrict__ wc,            // compact [B,S]
                          int* __restrict__ ecnt) {
    __shared__ float red[8];
    int b = blockIdx.x, t = threadIdx.x;
    int n = cnt[b];
    if (n == 0) {   // all masked -> reference softmax is uniform
        float u = 1.f / (float)S_;
        for (int j = t; j < S_; j += 256) {
            weights[b * S_ + j] = u;
            wc[b * S_ + j] = u;
        }
        if (t == 0) ecnt[b] = S_;
        return;
    }
    if (t == 0) ecnt[b] = n;
    const float* srow = scores + b * S_;
    float v[8];
    float mx = -3.402823466e38f;
    #pragma unroll
    for (int i = 0; i < 8; ++i) {
        int j = t + i * 256;
        v[i] = (j < n) ? srow[j] : -3.402823466e38f;
        mx = fmaxf(mx, v[i]);
    }
    #pragma unroll
    for (int o = 32; o; o >>= 1) mx = fmaxf(mx, __shfl_xor(mx, o));
    if ((t & 63) == 0) red[t >> 6] = mx;
    __syncthreads();
    mx = fmaxf(fmaxf(red[0], red[1]), fmaxf(red[2], red[3]));

    float e[8], sum = 0.f;
    #pragma unroll
    for (int i = 0; i < 8; ++i) { e[i] = __expf(v[i] - mx); sum += e[i]; }  // pad -> exp==0
    #pragma unroll
    for (int o = 32; o; o >>= 1) sum += __shfl_xor(sum, o);
    if ((t & 63) == 0) red[4 + (t >> 6)] = sum;
    __syncthreads();
    sum = red[4] + red[5] + red[6] + red[7];
    float inv = 1.f / sum;
    int nceil = (n + 127) & ~127;
    #pragma unroll
    for (int i = 0; i < 8; ++i) {
        int j = t + i * 256;
        if (j < n) {
            float w = e[i] * inv;
            weights[b * S_ + idx[b * S_ + j]] = w;
            wc[b * S_ + j] = w;
        } else if (j < nceil) {
            wc[b * S_ + j] = 0.f;
        }
    }
}

// ---------------- context = sum_j wc[j] * enc[idx[j]] over compacted rows ----------------
// 1024 blocks = (b, 16 chunks of 128 compacted rows); dead chunks early-exit.
__global__ void k_context(const float* __restrict__ enc,
                          const float* __restrict__ wc,
                          const int* __restrict__ idx,
                          const int* __restrict__ ecnt,
                          float* __restrict__ ctx) {
    int b  = blockIdx.x >> 4;
    int sc = blockIdx.x & 15;
    if (sc * 128 >= ecnt[b]) return;
    int t  = threadIdx.x;
    const int*   ip = idx + b * S_ + sc * 128;
    const float* wp = wc  + b * S_ + sc * 128;
    const float4* ebase = (const float4*)(enc + (size_t)b * S_ * E_);
    float4 acc = {0.f, 0.f, 0.f, 0.f};
    for (int s0 = 0; s0 < 128; s0 += 8) {
        float4 x[8]; float w[8];
        #pragma unroll
        for (int i = 0; i < 8; ++i) {
            int r = ip[s0 + i];
            w[i] = wp[s0 + i];
            x[i] = ebase[(size_t)r * (E_ / 4) + t];
        }
        #pragma unroll
        for (int i = 0; i < 8; ++i) {
            acc.x += w[i] * x[i].x; acc.y += w[i] * x[i].y;
            acc.z += w[i] * x[i].z; acc.w += w[i] * x[i].w;
        }
    }
    float* o = ctx + (size_t)b * E_ + t * 4;
    atomicAdd(o + 0, acc.x); atomicAdd(o + 1, acc.y);
    atomicAdd(o + 2, acc.z); atomicAdd(o + 3, acc.w);
}

extern "C" void kernel_launch(void* const* d_in, const int* in_sizes, int n_in,
                              void* d_out, int out_size, void* d_ws, size_t ws_size,
                              hipStream_t stream) {
    const float* dh   = (const float*)d_in[0];   // [64,1024]
    const float* enc  = (const float*)d_in[1];   // [64,2048,1024]
    const int*   mask = (const int*)  d_in[2];   // [64,2048]
    const float* wenc = (const float*)d_in[3];   // [512,1024]
    const float* wdec = (const float*)d_in[4];   // [512,1024]
    const float* wE   = (const float*)d_in[5];   // [1,512]

    float* out     = (float*)d_out;
    float* ctx     = out;                 // [64*1024]
    float* weights = out + B_ * E_;       // [64*2048]

    unsigned short* wencS = (unsigned short*)d_ws;                         // 1 MB
    float* df     = (float*)((char*)d_ws + (size_t)A_ * E_ * 2);           // 128 KB
    float* scores = df + B_ * A_;                                          // 512 KB
    int*   idx    = (int*)(scores + (size_t)B_ * S_);                      // 512 KB
    int*   cnt    = idx + (size_t)B_ * S_;                                 // 256 B
    int*   ecnt   = cnt + B_;                                              // 256 B
    float* wc     = (float*)(ecnt + B_);                                   // 512 KB

    hipMemsetAsync(out, 0, (size_t)(B_ * E_ + B_ * S_) * sizeof(float), stream);
    k_convert_wenc<<<256, 256, 0, stream>>>(wenc, wencS);
    k_dec_feat<<<B_ * 8, 256, 0, stream>>>(dh, wdec, df);
    k_compact<<<B_, 256, 0, stream>>>(mask, idx, cnt);
    k_scores<<<M_ / BM, 256, 0, stream>>>(enc, wencS, df, wE, idx, cnt, scores);
    k_softmax<<<B_, 256, 0, stream>>>(scores, idx, cnt, weights, wc, ecnt);
    k_context<<<B_ * 16, 256, 0, stream>>>(enc, wc, idx, ecnt, ctx);
}